// Round 12
// baseline (93.659 us; speedup 1.0000x reference)
//
#include <hip/hip_runtime.h>
#include <hip/hip_bf16.h>

#define NROWS 16384
#define DDIM  256
#define LOG2E 1.4426950408889634f
#define SCALE 7.213475204444817f   // (1/tau) * log2(e), tau = 0.2

typedef __attribute__((ext_vector_type(4))) float f32x4;
typedef __attribute__((ext_vector_type(2))) float f32x2;
typedef __attribute__((ext_vector_type(4))) int   i32x4;
typedef __attribute__((ext_vector_type(8))) int   i32x8;

#define UNIT_SCALE 0x7F7F7F7F   // e8m0 = 127 -> 2^0 = 1.0 in all 4 bytes

// ---------------------------------------------------------------------------
// Kernel 1: L2-normalize rows of z1,z2; quantize to OCP fp8 e4m3.
//   h1q = fp8(SCALE * h1_norm)  row-major (A side, pre-scaled for exp2)
//   h2t = fp8(h2_norm) in CHUNK-TRANSPOSED layout so simexp B-fragment loads
//         are fully coalesced 1KB global_load_dwordx4:
//         T[r>>4][ks(2)][hi(2)][q(4)][r&15][16B]  (4KB per 16-row block)
// exact fp32 diag logits diag5[i] = 5 * cos(z1_i, z2_i); zero rowsum.
// ---------------------------------------------------------------------------
__global__ __launch_bounds__(256) void prep_kernel(
    const float* __restrict__ z1, const float* __restrict__ z2,
    unsigned char* __restrict__ h1q, unsigned char* __restrict__ h2t,
    float* __restrict__ diag5, float* __restrict__ rowsum) {
  int tid = threadIdx.x;
  int w = tid >> 6, lane = tid & 63;
  int r = blockIdx.x * 4 + w;

  const float4 a = ((const float4*)z1)[r * 64 + lane];
  const float4 b = ((const float4*)z2)[r * 64 + lane];

  float ss1 = a.x * a.x + a.y * a.y + a.z * a.z + a.w * a.w;
  float ss2 = b.x * b.x + b.y * b.y + b.z * b.z + b.w * b.w;
  float dp  = a.x * b.x + a.y * b.y + a.z * b.z + a.w * b.w;
  #pragma unroll
  for (int m = 1; m <= 32; m <<= 1) {
    ss1 += __shfl_xor(ss1, m);
    ss2 += __shfl_xor(ss2, m);
    dp  += __shfl_xor(dp, m);
  }
  float inv1 = 1.0f / fmaxf(sqrtf(ss1), 1e-12f);
  float inv2 = 1.0f / fmaxf(sqrtf(ss2), 1e-12f);
  float s1 = inv1 * SCALE;         // fold 1/tau*log2e into A

  int p1 = __builtin_amdgcn_cvt_pk_fp8_f32(a.x * s1, a.y * s1, 0, false);
  p1     = __builtin_amdgcn_cvt_pk_fp8_f32(a.z * s1, a.w * s1, p1, true);
  int p2 = __builtin_amdgcn_cvt_pk_fp8_f32(b.x * inv2, b.y * inv2, 0, false);
  p2     = __builtin_amdgcn_cvt_pk_fp8_f32(b.z * inv2, b.w * inv2, p2, true);
  ((int*)h1q)[r * 64 + lane] = p1;

  // chunk-transposed h2t write: lane holds 4B at chunk c=lane>>2, sub=lane&3
  {
    int c = lane >> 2, sub = lane & 3;
    int off = (r >> 4) * 4096 + (c >> 3) * 2048 + (c & 1) * 1024 +
              ((c >> 1) & 3) * 256 + (r & 15) * 16 + sub * 4;
    *(int*)(h2t + off) = p2;
  }

  if (lane == 0) diag5[r] = dp * inv1 * inv2 * 5.0f;
  if (tid < 4) rowsum[blockIdx.x * 4 + tid] = 0.0f;  // 4096 blocks * 4 = 16384
}

// ---------------------------------------------------------------------------
// Kernel 2: rowsum_i = sum_j exp2(h1q_i . h2_j), PRODUCER/CONSUMER waves.
// r7-r11 invariant at ~78us: MFMA 70K cyc + VALU 80K cyc ADDITIVE -- with
// homogeneous waves, all waves convoy on the matrix pipe (MFMA burst, then
// all do exp while matrix idles). Fix: role-split the 8 waves of a 512-thr
// block: waves 0-3 PRODUCE (hold afr, 16 MFMA/phase, ds_write raw f32 acc),
// waves 4-7 CONSUME (ds_read acc, 32 exp2 + pk-adds into rowsum regs).
// Matrix pipe and trans pipe are driven by DIFFERENT waves every phase.
// 64 phases of 32 cols; acc slots double-buffered: 2 x 4waves x 8KB = 64KB.
// Per-SIMD/phase: MFMA 2x16x34.6=1106 cyc (binding) > consumer ~700 > LDS
// ~400 -> matrix-bound: 64 x 1106 = 71K cyc = 30us ideal.
// B frags from L2 via chunk-transposed h2t (coalesced dwordx4, lane*16).
// Producer regs <= ~115 (B in 16-reg halves, acc reused) -- under the 128
// remat cliff (r2-r5 lesson). Producers run at s_setprio(1).
// r8 PITFALL: global_load_lds imm offset shifts LDS dest too -- N/A here
// (no global_load_lds at all).
// ---------------------------------------------------------------------------
#define CSPL 8
#define NPH  64    // 2048 cols / 32 per phase

#define MFMA_S(Aop, Bop, Cop) \
  __builtin_amdgcn_mfma_scale_f32_16x16x128_f8f6f4( \
      Aop, Bop, Cop, 0, 0, 0, UNIT_SCALE, 0, UNIT_SCALE)

// Producer phase T: 16 MFMA on 32 cols, write 2x 16B/lane acc to LDS slot
#define PPHASE(T) do { \
  const char* b_ = Bp + (T) * 8192; \
  i32x4 B0 = *(const i32x4*)(b_); \
  i32x4 B1 = *(const i32x4*)(b_ + 1024); \
  i32x4 B2 = *(const i32x4*)(b_ + 2048); \
  i32x4 B3 = *(const i32x4*)(b_ + 3072); \
  union { i32x8 v; i32x4 h[2]; } u0_, u1_; \
  u0_.h[0] = B0; u0_.h[1] = B1; u1_.h[0] = B2; u1_.h[1] = B3; \
  f32x4 a_[4]; \
  _Pragma("unroll") for (int m = 0; m < 4; ++m) a_[m] = MFMA_S(afr[m][0], u0_.v, ZV); \
  _Pragma("unroll") for (int m = 0; m < 4; ++m) a_[m] = MFMA_S(afr[m][1], u1_.v, a_[m]); \
  i32x4 B4 = *(const i32x4*)(b_ + 4096); \
  i32x4 B5 = *(const i32x4*)(b_ + 5120); \
  i32x4 B6 = *(const i32x4*)(b_ + 6144); \
  i32x4 B7 = *(const i32x4*)(b_ + 7168); \
  char* s_ = Sw + (((T) & 1) << 15); \
  _Pragma("unroll") for (int m = 0; m < 4; ++m) *(f32x4*)(s_ + m * 1024) = a_[m]; \
  u0_.h[0] = B4; u0_.h[1] = B5; u1_.h[0] = B6; u1_.h[1] = B7; \
  _Pragma("unroll") for (int m = 0; m < 4; ++m) a_[m] = MFMA_S(afr[m][0], u0_.v, ZV); \
  _Pragma("unroll") for (int m = 0; m < 4; ++m) a_[m] = MFMA_S(afr[m][1], u1_.v, a_[m]); \
  _Pragma("unroll") for (int m = 0; m < 4; ++m) *(f32x4*)(s_ + 4096 + m * 1024) = a_[m]; \
} while (0)

// Consumer phase T: read the slot, 32 exp2, pk-add into rs2
#define CPHASE(T) do { \
  const char* s_ = Sw + (((T) & 1) << 15); \
  _Pragma("unroll") for (int m = 0; m < 4; ++m) { \
    f32x4 v0 = *(const f32x4*)(s_ + m * 1024); \
    f32x4 v1 = *(const f32x4*)(s_ + 4096 + m * 1024); \
    rs2[m][0] += (f32x2){__builtin_amdgcn_exp2f(v0[0]), __builtin_amdgcn_exp2f(v0[1])}; \
    rs2[m][1] += (f32x2){__builtin_amdgcn_exp2f(v0[2]), __builtin_amdgcn_exp2f(v0[3])}; \
    rs2[m][0] += (f32x2){__builtin_amdgcn_exp2f(v1[0]), __builtin_amdgcn_exp2f(v1[1])}; \
    rs2[m][1] += (f32x2){__builtin_amdgcn_exp2f(v1[2]), __builtin_amdgcn_exp2f(v1[3])}; \
  } \
} while (0)

__global__ __launch_bounds__(512) void simexp_kernel(
    const unsigned char* __restrict__ h1q, const unsigned char* __restrict__ h2t,
    float* __restrict__ rowsum) {
  __shared__ alignas(16) unsigned char sacc[2][32768];   // 64 KB acc ring

  int tid = threadIdx.x, w = tid >> 6, lane = tid & 63;
  int bx = blockIdx.x;
  int rb = bx >> 3;        // row block 0..63 (256 rows each)
  int cs = bx & 7;         // column split 0..7 == default XCD id (L2 locality)
  bool prod = (w < 4);
  int p = prod ? w : (w - 4);
  int row0 = rb * 256 + p * 64;

  // per-lane bases (both roles use the same slot addressing)
  const char* Bp = (const char*)h2t + (size_t)cs * 524288 + lane * 16;
  char* Sw = (char*)&sacc[0][0] + p * 8192 + lane * 16;

  const f32x4 ZV = {0.f, 0.f, 0.f, 0.f};
  i32x8 afr[4][2];
  f32x2 rs2[4][2];

  if (prod) {
    const char* h1b = (const char*)h1q;
    #pragma unroll
    for (int m = 0; m < 4; ++m)
      #pragma unroll
      for (int ks = 0; ks < 2; ++ks) {
        int row = row0 + m * 16 + (lane & 15);
        afr[m][ks] = *reinterpret_cast<const i32x8*>(
            h1b + row * 256 + ks * 128 + (lane >> 4) * 32);
      }
    #pragma unroll
    for (int m = 0; m < 4; ++m)
      #pragma unroll
      for (int ks = 0; ks < 2; ++ks)
        asm volatile("" : "+v"(afr[m][ks]));   // keep resident (no remat)
    __builtin_amdgcn_s_setprio(1);             // producers feed the MX pipe
  } else {
    #pragma unroll
    for (int m = 0; m < 4; ++m) {
      rs2[m][0] = (f32x2){0.f, 0.f};
      rs2[m][1] = (f32x2){0.f, 0.f};
    }
  }

  if (prod) PPHASE(0);
  __syncthreads();

  #pragma unroll 2
  for (int t = 1; t < NPH; ++t) {
    if (prod) PPHASE(t);
    else      CPHASE(t - 1);
    __syncthreads();
  }

  if (!prod) {
    CPHASE(NPH - 1);
    // reduce the 16 column-lanes (lane&15) and add to global rowsum
    #pragma unroll
    for (int m = 0; m < 4; ++m)
      #pragma unroll
      for (int q = 0; q < 2; ++q)
        #pragma unroll
        for (int c = 0; c < 2; ++c) {
          float v = rs2[m][q][c];
          v += __shfl_xor(v, 1);
          v += __shfl_xor(v, 2);
          v += __shfl_xor(v, 4);
          v += __shfl_xor(v, 8);
          if ((lane & 15) == 0)
            atomicAdd(&rowsum[row0 + m * 16 + (lane >> 4) * 4 + q * 2 + c], v);
        }
  }
}

// ---------------------------------------------------------------------------
// Kernel 3: loss = sum_i [ log(rowsum_i - exp(diag5_i)) - diag5_i ]
// ---------------------------------------------------------------------------
__global__ __launch_bounds__(1024) void loss_kernel(
    const float* __restrict__ rowsum, const float* __restrict__ diag5,
    float* __restrict__ out) {
  int tid = threadIdx.x;
  float s = 0.0f;
  for (int i = tid; i < NROWS; i += 1024) {
    float d5 = diag5[i];
    float de = __builtin_amdgcn_exp2f(d5 * LOG2E);
    s += logf(rowsum[i] - de) - d5;
  }
  #pragma unroll
  for (int m = 1; m <= 32; m <<= 1) s += __shfl_xor(s, m);
  __shared__ float wsum[16];
  if ((tid & 63) == 0) wsum[tid >> 6] = s;
  __syncthreads();
  if (tid == 0) {
    float t = 0.0f;
    #pragma unroll
    for (int i = 0; i < 16; ++i) t += wsum[i];
    out[0] = t;
  }
}

// ---------------------------------------------------------------------------
extern "C" void kernel_launch(void* const* d_in, const int* in_sizes, int n_in,
                              void* d_out, int out_size, void* d_ws, size_t ws_size,
                              hipStream_t stream) {
  const float* z1 = (const float*)d_in[0];
  const float* z2 = (const float*)d_in[1];

  char* ws = (char*)d_ws;
  unsigned char* h1q = (unsigned char*)(ws);             // 4 MB
  unsigned char* h2t = (unsigned char*)(ws + 4194304);   // 4 MB
  float* diag5 = (float*)(ws + 8421376);                 // 64 KB
  float* rowsm = (float*)(ws + 8486912);                 // 64 KB
  if (ws_size < 8552448) return;                         // fail loudly

  prep_kernel<<<4096, 256, 0, stream>>>(z1, z2, h1q, h2t, diag5, rowsm);
  simexp_kernel<<<512, 512, 0, stream>>>(h1q, h2t, rowsm);
  loss_kernel<<<1, 1024, 0, stream>>>(rowsm, diag5, (float*)d_out);
}

// Round 13
// 93.448 us; speedup vs baseline: 1.0023x; 1.0023x over previous
//
#include <hip/hip_runtime.h>
#include <hip/hip_bf16.h>

#define NROWS 16384
#define DDIM  256
#define LOG2E 1.4426950408889634f
#define SCALE 7.213475204444817f   // (1/tau) * log2(e), tau = 0.2

typedef __attribute__((ext_vector_type(4))) float f32x4;
typedef __attribute__((ext_vector_type(2))) float f32x2;
typedef __attribute__((ext_vector_type(4))) int   i32x4;
typedef __attribute__((ext_vector_type(8))) int   i32x8;

#define UNIT_SCALE 0x7F7F7F7F   // e8m0 = 127 -> 2^0 = 1.0 in all 4 bytes

// ---------------------------------------------------------------------------
// Kernel 1: L2-normalize rows of z1,z2; quantize to OCP fp8 e4m3.
//   h1q = fp8(SCALE * h1_norm)  row-major (A side, pre-scaled for exp2)
//   h2t = fp8(h2_norm) in CHUNK-TRANSPOSED layout so simexp B-fragment loads
//         are fully coalesced 1KB global_load_dwordx4:
//         T[r>>4][ks(2)][hi(2)][q(4)][r&15][16B]  (4KB per 16-row block)
// exact fp32 diag logits diag5[i] = 5 * cos(z1_i, z2_i); zero rowsum.
// ---------------------------------------------------------------------------
__global__ __launch_bounds__(256) void prep_kernel(
    const float* __restrict__ z1, const float* __restrict__ z2,
    unsigned char* __restrict__ h1q, unsigned char* __restrict__ h2t,
    float* __restrict__ diag5, float* __restrict__ rowsum) {
  int tid = threadIdx.x;
  int w = tid >> 6, lane = tid & 63;
  int r = blockIdx.x * 4 + w;

  const float4 a = ((const float4*)z1)[r * 64 + lane];
  const float4 b = ((const float4*)z2)[r * 64 + lane];

  float ss1 = a.x * a.x + a.y * a.y + a.z * a.z + a.w * a.w;
  float ss2 = b.x * b.x + b.y * b.y + b.z * b.z + b.w * b.w;
  float dp  = a.x * b.x + a.y * b.y + a.z * b.z + a.w * b.w;
  #pragma unroll
  for (int m = 1; m <= 32; m <<= 1) {
    ss1 += __shfl_xor(ss1, m);
    ss2 += __shfl_xor(ss2, m);
    dp  += __shfl_xor(dp, m);
  }
  float inv1 = 1.0f / fmaxf(sqrtf(ss1), 1e-12f);
  float inv2 = 1.0f / fmaxf(sqrtf(ss2), 1e-12f);
  float s1 = inv1 * SCALE;         // fold 1/tau*log2e into A

  int p1 = __builtin_amdgcn_cvt_pk_fp8_f32(a.x * s1, a.y * s1, 0, false);
  p1     = __builtin_amdgcn_cvt_pk_fp8_f32(a.z * s1, a.w * s1, p1, true);
  int p2 = __builtin_amdgcn_cvt_pk_fp8_f32(b.x * inv2, b.y * inv2, 0, false);
  p2     = __builtin_amdgcn_cvt_pk_fp8_f32(b.z * inv2, b.w * inv2, p2, true);
  ((int*)h1q)[r * 64 + lane] = p1;

  // chunk-transposed h2t write: lane holds 4B at chunk c=lane>>2, sub=lane&3
  {
    int c = lane >> 2, sub = lane & 3;
    int off = (r >> 4) * 4096 + (c >> 3) * 2048 + (c & 1) * 1024 +
              ((c >> 1) & 3) * 256 + (r & 15) * 16 + sub * 4;
    *(int*)(h2t + off) = p2;
  }

  if (lane == 0) diag5[r] = dp * inv1 * inv2 * 5.0f;
  if (tid < 4) rowsum[blockIdx.x * 4 + tid] = 0.0f;  // 4096 blocks * 4 = 16384
}

// ---------------------------------------------------------------------------
// Kernel 2: rowsum_i = sum_j exp2(h1q_i . h2_j) via MX-scaled fp8 MFMA.
// LDS-FREE, BARRIER-FREE free-run (r11 structure) + 4 WAVES/SIMD (this
// round's change: CSPL 8->16, grid 512->1024 = 4 blocks/CU).
// WHY: the matrix pipe is a per-CU shared unit needing an MFMA every
// ~8.6 cyc to saturate; a wave feeds it only ~140 cyc out of each ~600-cyc
// tile cycle (rest = exp2 + loads). r11 ran 2 waves/SIMD -> coverage ~47%
// (measured MfmaUtil 36-42%). 4 desynced waves/SIMD -> coverage ~93%.
// VGPR 112 -> exactly 4 waves/SIMD fits (448<=512). No barriers, so waves
// drift apart naturally and interleave their MFMA bursts.
// B frags straight from L2 (chunk-transposed h2t, coalesced dwordx4);
// named double-buffer bufA/bufB (rule #20); zero-C trick kills acc-init.
// Each wave: 64 rows x 1024 cols of its cs-strip = 32 tiles of 32 cols.
// Per-XCD L2 B-traffic ~3.2 TB/s < 4.3 ceiling; working set 512KB/XCD.
// ---------------------------------------------------------------------------
#define CSPL 16

#define LOADSET(B, P0, P1) do { \
  B[0] = *reinterpret_cast<const i32x4*>(P0); \
  B[1] = *reinterpret_cast<const i32x4*>(P0 + 1024); \
  B[2] = *reinterpret_cast<const i32x4*>(P0 + 2048); \
  B[3] = *reinterpret_cast<const i32x4*>(P0 + 3072); \
  B[4] = *reinterpret_cast<const i32x4*>(P1); \
  B[5] = *reinterpret_cast<const i32x4*>(P1 + 1024); \
  B[6] = *reinterpret_cast<const i32x4*>(P1 + 2048); \
  B[7] = *reinterpret_cast<const i32x4*>(P1 + 3072); \
  P0 += 8192; P1 += 8192; } while (0)

#define MFMA_S(Aop, Bop, Cop) \
  __builtin_amdgcn_mfma_scale_f32_16x16x128_f8f6f4( \
      Aop, Bop, Cop, 0, 0, 0, UNIT_SCALE, 0, UNIT_SCALE)

#define COMPUTE(B) do { \
  union { i32x8 v; i32x4 h[2]; } u00, u01, u10, u11; \
  u00.h[0] = B[0]; u00.h[1] = B[1]; u01.h[0] = B[2]; u01.h[1] = B[3]; \
  u10.h[0] = B[4]; u10.h[1] = B[5]; u11.h[0] = B[6]; u11.h[1] = B[7]; \
  f32x4 a0[4], a1[4]; \
  _Pragma("unroll") for (int m = 0; m < 4; ++m) a0[m] = MFMA_S(afr[m][0], u00.v, ZV); \
  _Pragma("unroll") for (int m = 0; m < 4; ++m) a1[m] = MFMA_S(afr[m][0], u10.v, ZV); \
  _Pragma("unroll") for (int m = 0; m < 4; ++m) a0[m] = MFMA_S(afr[m][1], u01.v, a0[m]); \
  _Pragma("unroll") for (int m = 0; m < 4; ++m) a1[m] = MFMA_S(afr[m][1], u11.v, a1[m]); \
  _Pragma("unroll") for (int m = 0; m < 4; ++m) { \
    rs2[m][0] += (f32x2){__builtin_amdgcn_exp2f(a0[m][0]), __builtin_amdgcn_exp2f(a0[m][1])}; \
    rs2[m][1] += (f32x2){__builtin_amdgcn_exp2f(a0[m][2]), __builtin_amdgcn_exp2f(a0[m][3])}; \
    rs2[m][0] += (f32x2){__builtin_amdgcn_exp2f(a1[m][0]), __builtin_amdgcn_exp2f(a1[m][1])}; \
    rs2[m][1] += (f32x2){__builtin_amdgcn_exp2f(a1[m][2]), __builtin_amdgcn_exp2f(a1[m][3])}; \
  } } while (0)

__global__ __launch_bounds__(256) void simexp_kernel(
    const unsigned char* __restrict__ h1q, const unsigned char* __restrict__ h2t,
    float* __restrict__ rowsum) {
  int tid = threadIdx.x, w = tid >> 6, lane = tid & 63;
  int bx = blockIdx.x;
  int rb = bx >> 4;        // row block 0..63 (256 rows each)
  int cs = bx & 15;        // column split 0..15 (XCD x serves strips x, x+8)
  int row0 = rb * 256 + w * 64;

  const char* h1b = (const char*)h1q;

  // A fragments: 4 row-subtiles x 2 k128-steps, 32 fp8 each -> 64 VGPRs
  i32x8 afr[4][2];
  #pragma unroll
  for (int m = 0; m < 4; ++m)
    #pragma unroll
    for (int ks = 0; ks < 2; ++ks) {
      int row = row0 + m * 16 + (lane & 15);
      int off = row * 256 + ks * 128 + (lane >> 4) * 32;   // 32B aligned
      afr[m][ks] = *reinterpret_cast<const i32x8*>(h1b + off);
    }
  #pragma unroll
  for (int m = 0; m < 4; ++m)
    #pragma unroll
    for (int ks = 0; ks < 2; ++ks)
      asm volatile("" : "+v"(afr[m][ks]));   // keep resident (no remat)

  // B-fragment base pointers into the chunk-transposed strip:
  // strip = 1024 cols * 256B = 256KB; per 32-col tile: n=0 at +0, n=1 at
  // +4096; per-lane addr = base + lane*16; bump 8192/tile.
  const char* Bp0 = (const char*)h2t + (size_t)cs * 262144 + lane * 16;
  const char* Bp1 = Bp0 + 4096;

  const f32x4 ZV = {0.f, 0.f, 0.f, 0.f};
  f32x2 rs2[4][2];
  #pragma unroll
  for (int m = 0; m < 4; ++m) {
    rs2[m][0] = (f32x2){0.f, 0.f};
    rs2[m][1] = (f32x2){0.f, 0.f};
  }

  i32x4 bufA[8], bufB[8];
  LOADSET(bufA, Bp0, Bp1);          // prime tile 0

  for (int jt2 = 0; jt2 < 16; ++jt2) {
    LOADSET(bufB, Bp0, Bp1);        // prefetch tile 2*jt2+1
    COMPUTE(bufA);                  // compute tile 2*jt2
    LOADSET(bufA, Bp0, Bp1);        // prefetch tile 2*jt2+2 (last iter: OOB
                                    // into ws slack, never computed)
    COMPUTE(bufB);                  // compute tile 2*jt2+1
  }

  // reduce the 16 column-lanes (lane&15) and add to global rowsum
  #pragma unroll
  for (int m = 0; m < 4; ++m)
    #pragma unroll
    for (int p = 0; p < 2; ++p)
      #pragma unroll
      for (int c = 0; c < 2; ++c) {
        float v = rs2[m][p][c];
        v += __shfl_xor(v, 1);
        v += __shfl_xor(v, 2);
        v += __shfl_xor(v, 4);
        v += __shfl_xor(v, 8);
        if ((lane & 15) == 0)
          atomicAdd(&rowsum[row0 + m * 16 + (lane >> 4) * 4 + p * 2 + c], v);
      }
}

// ---------------------------------------------------------------------------
// Kernel 3: loss = sum_i [ log(rowsum_i - exp(diag5_i)) - diag5_i ]
// ---------------------------------------------------------------------------
__global__ __launch_bounds__(1024) void loss_kernel(
    const float* __restrict__ rowsum, const float* __restrict__ diag5,
    float* __restrict__ out) {
  int tid = threadIdx.x;
  float s = 0.0f;
  for (int i = tid; i < NROWS; i += 1024) {
    float d5 = diag5[i];
    float de = __builtin_amdgcn_exp2f(d5 * LOG2E);
    s += logf(rowsum[i] - de) - d5;
  }
  #pragma unroll
  for (int m = 1; m <= 32; m <<= 1) s += __shfl_xor(s, m);
  __shared__ float wsum[16];
  if ((tid & 63) == 0) wsum[tid >> 6] = s;
  __syncthreads();
  if (tid == 0) {
    float t = 0.0f;
    #pragma unroll
    for (int i = 0; i < 16; ++i) t += wsum[i];
    out[0] = t;
  }
}

// ---------------------------------------------------------------------------
extern "C" void kernel_launch(void* const* d_in, const int* in_sizes, int n_in,
                              void* d_out, int out_size, void* d_ws, size_t ws_size,
                              hipStream_t stream) {
  const float* z1 = (const float*)d_in[0];
  const float* z2 = (const float*)d_in[1];

  char* ws = (char*)d_ws;
  unsigned char* h1q = (unsigned char*)(ws);             // 4 MB
  unsigned char* h2t = (unsigned char*)(ws + 4194304);   // 4 MB + 32KB slack
  float* diag5 = (float*)(ws + 8421376);                 // 64 KB
  float* rowsm = (float*)(ws + 8486912);                 // 64 KB
  if (ws_size < 8552448) return;                         // fail loudly

  prep_kernel<<<4096, 256, 0, stream>>>(z1, z2, h1q, h2t, diag5, rowsm);
  simexp_kernel<<<1024, 256, 0, stream>>>(h1q, h2t, rowsm);
  loss_kernel<<<1, 1024, 0, stream>>>(rowsm, diag5, (float*)d_out);
}

// Round 14
// 92.279 us; speedup vs baseline: 1.0150x; 1.0127x over previous
//
#include <hip/hip_runtime.h>
#include <hip/hip_bf16.h>

#define NROWS 16384
#define DDIM  256
#define LOG2E 1.4426950408889634f
#define SCALE 7.213475204444817f   // (1/tau) * log2(e), tau = 0.2

typedef __attribute__((ext_vector_type(4))) float f32x4;
typedef __attribute__((ext_vector_type(2))) float f32x2;
typedef __attribute__((ext_vector_type(4))) int   i32x4;
typedef __attribute__((ext_vector_type(8))) int   i32x8;

#define UNIT_SCALE 0x7F7F7F7F   // e8m0 = 127 -> 2^0 = 1.0 in all 4 bytes

// ---------------------------------------------------------------------------
// Kernel 1: L2-normalize rows of z1,z2; quantize to OCP fp8 e4m3.
//   h1q = fp8(SCALE * h1_norm)  row-major (A side, pre-scaled for exp2)
//   h2t = fp8(h2_norm) in CHUNK-TRANSPOSED layout so simexp B-fragment loads
//         are fully coalesced 1KB global_load_dwordx4:
//         T[r>>4][ks(2)][hi(2)][q(4)][r&15][16B]  (4KB per 16-row block)
// exact fp32 diag logits diag5[i] = 5 * cos(z1_i, z2_i); zero rowsum.
// ---------------------------------------------------------------------------
__global__ __launch_bounds__(256) void prep_kernel(
    const float* __restrict__ z1, const float* __restrict__ z2,
    unsigned char* __restrict__ h1q, unsigned char* __restrict__ h2t,
    float* __restrict__ diag5, float* __restrict__ rowsum) {
  int tid = threadIdx.x;
  int w = tid >> 6, lane = tid & 63;
  int r = blockIdx.x * 4 + w;

  const float4 a = ((const float4*)z1)[r * 64 + lane];
  const float4 b = ((const float4*)z2)[r * 64 + lane];

  float ss1 = a.x * a.x + a.y * a.y + a.z * a.z + a.w * a.w;
  float ss2 = b.x * b.x + b.y * b.y + b.z * b.z + b.w * b.w;
  float dp  = a.x * b.x + a.y * b.y + a.z * b.z + a.w * b.w;
  #pragma unroll
  for (int m = 1; m <= 32; m <<= 1) {
    ss1 += __shfl_xor(ss1, m);
    ss2 += __shfl_xor(ss2, m);
    dp  += __shfl_xor(dp, m);
  }
  float inv1 = 1.0f / fmaxf(sqrtf(ss1), 1e-12f);
  float inv2 = 1.0f / fmaxf(sqrtf(ss2), 1e-12f);
  float s1 = inv1 * SCALE;         // fold 1/tau*log2e into A

  int p1 = __builtin_amdgcn_cvt_pk_fp8_f32(a.x * s1, a.y * s1, 0, false);
  p1     = __builtin_amdgcn_cvt_pk_fp8_f32(a.z * s1, a.w * s1, p1, true);
  int p2 = __builtin_amdgcn_cvt_pk_fp8_f32(b.x * inv2, b.y * inv2, 0, false);
  p2     = __builtin_amdgcn_cvt_pk_fp8_f32(b.z * inv2, b.w * inv2, p2, true);
  ((int*)h1q)[r * 64 + lane] = p1;

  // chunk-transposed h2t write: lane holds 4B at chunk c=lane>>2, sub=lane&3
  {
    int c = lane >> 2, sub = lane & 3;
    int off = (r >> 4) * 4096 + (c >> 3) * 2048 + (c & 1) * 1024 +
              ((c >> 1) & 3) * 256 + (r & 15) * 16 + sub * 4;
    *(int*)(h2t + off) = p2;
  }

  if (lane == 0) diag5[r] = dp * inv1 * inv2 * 5.0f;
  if (tid < 4) rowsum[blockIdx.x * 4 + tid] = 0.0f;  // 4096 blocks * 4 = 16384
}

// ---------------------------------------------------------------------------
// Kernel 2: rowsum_i = sum_j exp2(h1q_i . h2_j), PRODUCER/CONSUMER waves.
// r12 structure, FIXED: __launch_bounds__(512, 2) gives the allocator a
// 256-VGPR budget. r12's silent failure: with no min-waves arg the compiler
// targeted 8 waves/EU -> 64 VGPR -> producers' afr rematerialized into the
// phase loop (the r2-r5 failure mode), destroying the role split. Producer
// demand ~127 regs: even a squeeze to the 128 cliff fits -> no remat.
// Roles per 512-thr block (1 block/CU): waves 0-3 PRODUCE (hold afr, 16
// MFMA/phase -> ds_write raw f32 acc), waves 4-7 CONSUME (ds_read, 32 exp2 +
// pk-adds). Matrix unit (1 producer wave/SIMD, ~550 cyc/phase) and
// trans/VALU (1 consumer wave/SIMD, ~450 cyc/phase) run CONCURRENTLY (m114).
// 64 phases/block, double-buffered 2x32KB acc slots; producers setprio(1).
// B frags from L2 via chunk-transposed h2t (coalesced dwordx4, lane*16).
// ---------------------------------------------------------------------------
#define CSPL 8
#define NPH  64    // 2048 cols / 32 per phase

#define MFMA_S(Aop, Bop, Cop) \
  __builtin_amdgcn_mfma_scale_f32_16x16x128_f8f6f4( \
      Aop, Bop, Cop, 0, 0, 0, UNIT_SCALE, 0, UNIT_SCALE)

// Producer phase T: 16 MFMA on 32 cols, write 2x 16B/lane acc to LDS slot
#define PPHASE(T) do { \
  const char* b_ = Bp + (T) * 8192; \
  i32x4 B0 = *(const i32x4*)(b_); \
  i32x4 B1 = *(const i32x4*)(b_ + 1024); \
  i32x4 B2 = *(const i32x4*)(b_ + 2048); \
  i32x4 B3 = *(const i32x4*)(b_ + 3072); \
  union { i32x8 v; i32x4 h[2]; } u0_, u1_; \
  u0_.h[0] = B0; u0_.h[1] = B1; u1_.h[0] = B2; u1_.h[1] = B3; \
  f32x4 a_[4]; \
  _Pragma("unroll") for (int m = 0; m < 4; ++m) a_[m] = MFMA_S(afr[m][0], u0_.v, ZV); \
  _Pragma("unroll") for (int m = 0; m < 4; ++m) a_[m] = MFMA_S(afr[m][1], u1_.v, a_[m]); \
  i32x4 B4 = *(const i32x4*)(b_ + 4096); \
  i32x4 B5 = *(const i32x4*)(b_ + 5120); \
  i32x4 B6 = *(const i32x4*)(b_ + 6144); \
  i32x4 B7 = *(const i32x4*)(b_ + 7168); \
  char* s_ = Sw + (((T) & 1) << 15); \
  _Pragma("unroll") for (int m = 0; m < 4; ++m) *(f32x4*)(s_ + m * 1024) = a_[m]; \
  u0_.h[0] = B4; u0_.h[1] = B5; u1_.h[0] = B6; u1_.h[1] = B7; \
  _Pragma("unroll") for (int m = 0; m < 4; ++m) a_[m] = MFMA_S(afr[m][0], u0_.v, ZV); \
  _Pragma("unroll") for (int m = 0; m < 4; ++m) a_[m] = MFMA_S(afr[m][1], u1_.v, a_[m]); \
  _Pragma("unroll") for (int m = 0; m < 4; ++m) *(f32x4*)(s_ + 4096 + m * 1024) = a_[m]; \
} while (0)

// Consumer phase T: read the slot, 32 exp2, pk-add into rs2
#define CPHASE(T) do { \
  const char* s_ = Sw + (((T) & 1) << 15); \
  _Pragma("unroll") for (int m = 0; m < 4; ++m) { \
    f32x4 v0 = *(const f32x4*)(s_ + m * 1024); \
    f32x4 v1 = *(const f32x4*)(s_ + 4096 + m * 1024); \
    rs2[m][0] += (f32x2){__builtin_amdgcn_exp2f(v0[0]), __builtin_amdgcn_exp2f(v0[1])}; \
    rs2[m][1] += (f32x2){__builtin_amdgcn_exp2f(v0[2]), __builtin_amdgcn_exp2f(v0[3])}; \
    rs2[m][0] += (f32x2){__builtin_amdgcn_exp2f(v1[0]), __builtin_amdgcn_exp2f(v1[1])}; \
    rs2[m][1] += (f32x2){__builtin_amdgcn_exp2f(v1[2]), __builtin_amdgcn_exp2f(v1[3])}; \
  } \
} while (0)

__global__ __launch_bounds__(512, 2) void simexp_kernel(
    const unsigned char* __restrict__ h1q, const unsigned char* __restrict__ h2t,
    float* __restrict__ rowsum) {
  __shared__ alignas(16) unsigned char sacc[2][32768];   // 64 KB acc ring

  int tid = threadIdx.x, w = tid >> 6, lane = tid & 63;
  int bx = blockIdx.x;
  int rb = bx >> 3;        // row block 0..63 (256 rows each)
  int cs = bx & 7;         // column split 0..7 == default XCD id (L2 locality)
  bool prod = (w < 4);
  int p = prod ? w : (w - 4);
  int row0 = rb * 256 + p * 64;

  // per-lane bases (both roles use the same slot addressing)
  const char* Bp = (const char*)h2t + (size_t)cs * 524288 + lane * 16;
  char* Sw = (char*)&sacc[0][0] + p * 8192 + lane * 16;

  const f32x4 ZV = {0.f, 0.f, 0.f, 0.f};
  i32x8 afr[4][2];
  f32x2 rs2[4][2];

  if (prod) {
    const char* h1b = (const char*)h1q;
    #pragma unroll
    for (int m = 0; m < 4; ++m)
      #pragma unroll
      for (int ks = 0; ks < 2; ++ks) {
        int row = row0 + m * 16 + (lane & 15);
        afr[m][ks] = *reinterpret_cast<const i32x8*>(
            h1b + row * 256 + ks * 128 + (lane >> 4) * 32);
      }
    #pragma unroll
    for (int m = 0; m < 4; ++m)
      #pragma unroll
      for (int ks = 0; ks < 2; ++ks)
        asm volatile("" : "+v"(afr[m][ks]));   // keep resident (no remat)
    __builtin_amdgcn_s_setprio(1);             // producers feed the MX pipe
  } else {
    #pragma unroll
    for (int m = 0; m < 4; ++m) {
      rs2[m][0] = (f32x2){0.f, 0.f};
      rs2[m][1] = (f32x2){0.f, 0.f};
    }
  }

  if (prod) PPHASE(0);
  __syncthreads();

  for (int t = 1; t < NPH; ++t) {
    if (prod) PPHASE(t);
    else      CPHASE(t - 1);
    __syncthreads();
  }

  if (!prod) {
    CPHASE(NPH - 1);
    // reduce the 16 column-lanes (lane&15) and add to global rowsum
    #pragma unroll
    for (int m = 0; m < 4; ++m)
      #pragma unroll
      for (int q = 0; q < 2; ++q)
        #pragma unroll
        for (int c = 0; c < 2; ++c) {
          float v = rs2[m][q][c];
          v += __shfl_xor(v, 1);
          v += __shfl_xor(v, 2);
          v += __shfl_xor(v, 4);
          v += __shfl_xor(v, 8);
          if ((lane & 15) == 0)
            atomicAdd(&rowsum[row0 + m * 16 + (lane >> 4) * 4 + q * 2 + c], v);
        }
  }
}

// ---------------------------------------------------------------------------
// Kernel 3: loss = sum_i [ log(rowsum_i - exp(diag5_i)) - diag5_i ]
// ---------------------------------------------------------------------------
__global__ __launch_bounds__(1024) void loss_kernel(
    const float* __restrict__ rowsum, const float* __restrict__ diag5,
    float* __restrict__ out) {
  int tid = threadIdx.x;
  float s = 0.0f;
  for (int i = tid; i < NROWS; i += 1024) {
    float d5 = diag5[i];
    float de = __builtin_amdgcn_exp2f(d5 * LOG2E);
    s += logf(rowsum[i] - de) - d5;
  }
  #pragma unroll
  for (int m = 1; m <= 32; m <<= 1) s += __shfl_xor(s, m);
  __shared__ float wsum[16];
  if ((tid & 63) == 0) wsum[tid >> 6] = s;
  __syncthreads();
  if (tid == 0) {
    float t = 0.0f;
    #pragma unroll
    for (int i = 0; i < 16; ++i) t += wsum[i];
    out[0] = t;
  }
}

// ---------------------------------------------------------------------------
extern "C" void kernel_launch(void* const* d_in, const int* in_sizes, int n_in,
                              void* d_out, int out_size, void* d_ws, size_t ws_size,
                              hipStream_t stream) {
  const float* z1 = (const float*)d_in[0];
  const float* z2 = (const float*)d_in[1];

  char* ws = (char*)d_ws;
  unsigned char* h1q = (unsigned char*)(ws);             // 4 MB
  unsigned char* h2t = (unsigned char*)(ws + 4194304);   // 4 MB
  float* diag5 = (float*)(ws + 8421376);                 // 64 KB
  float* rowsm = (float*)(ws + 8486912);                 // 64 KB
  if (ws_size < 8552448) return;                         // fail loudly

  prep_kernel<<<4096, 256, 0, stream>>>(z1, z2, h1q, h2t, diag5, rowsm);
  simexp_kernel<<<512, 512, 0, stream>>>(h1q, h2t, rowsm);
  loss_kernel<<<1, 1024, 0, stream>>>(rowsm, diag5, (float*)d_out);
}